// Round 1
// baseline (599.298 us; speedup 1.0000x reference)
//
#include <hip/hip_runtime.h>

// DualSPRTLinear: out[b,s,o] = sum_i x[b,s,i] * (ternary[o,i] * scales[(o*IN_F+i)/128])
// => bf16 MFMA GEMM: M=8192 (b*s), N=4096 (o), K=4096 (i), B stored N x K ("B^T" form).
// Strategy: dequant/downcast passes into d_ws, then m97-structure 128x128 MFMA GEMM.

typedef __attribute__((ext_vector_type(8))) short      bf16x8;
typedef __attribute__((ext_vector_type(4))) float      f32x4;
typedef __attribute__((ext_vector_type(8))) float      f32x8;
typedef __attribute__((ext_vector_type(8))) unsigned short u16x8;
typedef __attribute__((ext_vector_type(4))) int        i32x4;

#define M_DIM 8192
#define N_DIM 4096
#define K_DIM 4096
#define BM 128
#define BN 128
#define BK 32

// fp32 -> bf16 round-to-nearest-even (finite inputs only, which holds here)
__device__ __forceinline__ unsigned short f2bf(float f) {
  union { float f; unsigned u; } v; v.f = f;
  unsigned u = v.u;
  u += 0x7FFFu + ((u >> 16) & 1u);
  return (unsigned short)(u >> 16);
}

// x: fp32 [M][K] -> bf16 [M][K]. n8 = M*K/8.
__global__ void cvt_x_kernel(const float* __restrict__ x,
                             unsigned short* __restrict__ y, int n8) {
  int stride = gridDim.x * blockDim.x;
  for (int i = blockIdx.x * blockDim.x + threadIdx.x; i < n8; i += stride) {
    f32x8 f = ((const f32x8*)x)[i];
    u16x8 o;
#pragma unroll
    for (int j = 0; j < 8; ++j) o[j] = f2bf(f[j]);
    ((u16x8*)y)[i] = o;
  }
}

// ternary (int32 per harness convention) [N][K] * group scale -> bf16 [N][K].
// Chunk i covers elements [8i, 8i+8); group id = 8i/128 = i>>4 (GS=128 divides 8).
__global__ void cvt_w_kernel(const int* __restrict__ t, const float* __restrict__ s,
                             unsigned short* __restrict__ w, int n8) {
  int stride = gridDim.x * blockDim.x;
  for (int i = blockIdx.x * blockDim.x + threadIdx.x; i < n8; i += stride) {
    i32x4 a = ((const i32x4*)t)[2 * i + 0];
    i32x4 b = ((const i32x4*)t)[2 * i + 1];
    float sc = s[i >> 4];
    u16x8 o;
    o[0] = f2bf((float)a[0] * sc);
    o[1] = f2bf((float)a[1] * sc);
    o[2] = f2bf((float)a[2] * sc);
    o[3] = f2bf((float)a[3] * sc);
    o[4] = f2bf((float)b[0] * sc);
    o[5] = f2bf((float)b[1] * sc);
    o[6] = f2bf((float)b[2] * sc);
    o[7] = f2bf((float)b[3] * sc);
    ((u16x8*)w)[i] = o;
  }
}

// m97-structure GEMM: A [M][K] bf16 row-major, B [N][K] bf16 row-major (B^T input),
// C [M][N] fp32. 256 threads = 4 waves (2x2), wave tile 64x64 = 4x4 16x16 frags.
// Staging: global_load_lds width=16, linear LDS (required: dest = wave base + lane*16).
__global__ void gemm_bt_kernel(const unsigned short* __restrict__ A,
                               const unsigned short* __restrict__ B,
                               float* __restrict__ C) {
  __shared__ __align__(16) unsigned short sA[BM * BK];  // 8 KB
  __shared__ __align__(16) unsigned short sB[BN * BK];  // 8 KB

  const int tid  = threadIdx.x;
  const int lane = tid & 63;
  const int wave = tid >> 6;
  const int wm = wave >> 1;   // 0..1
  const int wn = wave & 1;    // 0..1

  // XCD-bijective swizzle: grid = 2048 (= 64*32), 2048 % 8 == 0 -> simple form OK.
  const int nwg = gridDim.x;
  const int cpx = nwg >> 3;
  const int wg  = (blockIdx.x & 7) * cpx + (blockIdx.x >> 3);
  const int nN  = N_DIM / BN;           // 32
  const int bm  = wg / nN;
  const int bn  = wg % nN;

  const unsigned short* Ab = A + (size_t)bm * BM * K_DIM;
  const unsigned short* Bb = B + (size_t)bn * BN * K_DIM;

  // Staging chunk t in [0,512): LDS bytes [16t,16t+16) <- global row t>>2, col8 (t&3)*8.
  // Issue i (0/1), wave w: uniform LDS base = i*4096 + w*1024 bytes; HW adds lane*16.
  // Lane's chunk t = i*256 + tid, so global offset below matches the linear LDS fill.
  const int ga0 = (tid >> 2) * K_DIM + (tid & 3) * 8;        // rows 0..63
  const int ga1 = ga0 + 64 * K_DIM;                          // rows 64..127

  const f32x4 fzero = {0.f, 0.f, 0.f, 0.f};
  f32x4 acc[4][4];
#pragma unroll
  for (int mr = 0; mr < 4; ++mr)
#pragma unroll
    for (int nr = 0; nr < 4; ++nr) acc[mr][nr] = fzero;

  const int r  = lane & 15;
  const int kq = lane >> 4;

  for (int k0 = 0; k0 < K_DIM; k0 += BK) {
    // ---- stage A,B tiles (4 x global_load_lds_dwordx4 per thread-equivalent) ----
    __builtin_amdgcn_global_load_lds(
        (const __attribute__((address_space(1))) void*)(Ab + ga0 + k0),
        (__attribute__((address_space(3))) void*)(sA + wave * 512), 16, 0, 0);
    __builtin_amdgcn_global_load_lds(
        (const __attribute__((address_space(1))) void*)(Ab + ga1 + k0),
        (__attribute__((address_space(3))) void*)(sA + 2048 + wave * 512), 16, 0, 0);
    __builtin_amdgcn_global_load_lds(
        (const __attribute__((address_space(1))) void*)(Bb + ga0 + k0),
        (__attribute__((address_space(3))) void*)(sB + wave * 512), 16, 0, 0);
    __builtin_amdgcn_global_load_lds(
        (const __attribute__((address_space(1))) void*)(Bb + ga1 + k0),
        (__attribute__((address_space(3))) void*)(sB + 2048 + wave * 512), 16, 0, 0);

    __syncthreads();  // waitcnt vmcnt(0) + barrier: tiles ready

    // ---- fragments: one ds_read_b128 each (8 bf16 spanning full BK=32) ----
    bf16x8 af[4], bfr[4];
#pragma unroll
    for (int mr = 0; mr < 4; ++mr)
      af[mr] = *(const bf16x8*)&sA[(wm * 64 + mr * 16 + r) * BK + kq * 8];
#pragma unroll
    for (int nr = 0; nr < 4; ++nr)
      bfr[nr] = *(const bf16x8*)&sB[(wn * 64 + nr * 16 + r) * BK + kq * 8];

#pragma unroll
    for (int mr = 0; mr < 4; ++mr)
#pragma unroll
      for (int nr = 0; nr < 4; ++nr)
        acc[mr][nr] = __builtin_amdgcn_mfma_f32_16x16x32_bf16(
            af[mr], bfr[nr], acc[mr][nr], 0, 0, 0);

    __syncthreads();  // protect LDS from next iteration's staging
  }

  // ---- epilogue: C/D map col = lane&15, row = (lane>>4)*4 + j (m89/m91 verified) ----
  const int row0 = bm * BM + wm * 64 + (lane >> 4) * 4;
  const int col0 = bn * BN + wn * 64 + (lane & 15);
#pragma unroll
  for (int mr = 0; mr < 4; ++mr) {
#pragma unroll
    for (int nr = 0; nr < 4; ++nr) {
#pragma unroll
      for (int j = 0; j < 4; ++j) {
        C[(size_t)(row0 + mr * 16 + j) * N_DIM + (col0 + nr * 16)] = acc[mr][nr][j];
      }
    }
  }
}

extern "C" void kernel_launch(void* const* d_in, const int* in_sizes, int n_in,
                              void* d_out, int out_size, void* d_ws, size_t ws_size,
                              hipStream_t stream) {
  const float* x      = (const float*)d_in[0];   // [4,2048,4096] fp32
  const int*   tern   = (const int*)d_in[1];     // [4096,4096] int (harness: integer -> int32)
  const float* scales = (const float*)d_in[2];   // [131072] fp32
  float* out = (float*)d_out;                    // [4,2048,4096] fp32

  unsigned short* xb = (unsigned short*)d_ws;                         // 64 MB bf16 x
  unsigned short* wb = (unsigned short*)d_ws + (size_t)M_DIM * K_DIM; // 32 MB bf16 W

  cvt_x_kernel<<<2048, 256, 0, stream>>>(x, xb, M_DIM * K_DIM / 8);
  cvt_w_kernel<<<2048, 256, 0, stream>>>(tern, scales, wb, N_DIM * K_DIM / 8);

  const int grid = (M_DIM / BM) * (N_DIM / BN);  // 64 * 32 = 2048
  gemm_bt_kernel<<<grid, 256, 0, stream>>>(xb, wb, out);
}

// Round 2
// 488.012 us; speedup vs baseline: 1.2280x; 1.2280x over previous
//
#include <hip/hip_runtime.h>

// DualSPRTLinear: out = x @ W^T, W = dequant(ternary, group scales).
// bf16 MFMA GEMM M=8192, N=4096, K=4096, B stored [N][K] (B^T form).
// Round 2: 256x256 8-phase template (T1 XCD swizzle + T2 LDS XOR swizzle +
// T3/T4 phase interleave with counted vmcnt + T5 setprio), per m201.

typedef __attribute__((ext_vector_type(8))) short      bf16x8;
typedef __attribute__((ext_vector_type(4))) float      f32x4;
typedef __attribute__((ext_vector_type(8))) float      f32x8;
typedef __attribute__((ext_vector_type(8))) unsigned short u16x8;
typedef __attribute__((ext_vector_type(4))) int        i32x4;

#define M_DIM 8192
#define N_DIM 4096
#define K_DIM 4096
#define BM 256
#define BN 256
#define BK 64
#define NT (K_DIM / BK)   // 64 K-tiles
#define THREADS 512

__device__ __forceinline__ unsigned short f2bf(float f) {
  union { float f; unsigned u; } v; v.f = f;
  unsigned u = v.u;
  u += 0x7FFFu + ((u >> 16) & 1u);
  return (unsigned short)(u >> 16);
}

__global__ void cvt_x_kernel(const float* __restrict__ x,
                             unsigned short* __restrict__ y, int n8) {
  int stride = gridDim.x * blockDim.x;
  for (int i = blockIdx.x * blockDim.x + threadIdx.x; i < n8; i += stride) {
    f32x8 f = ((const f32x8*)x)[i];
    u16x8 o;
#pragma unroll
    for (int j = 0; j < 8; ++j) o[j] = f2bf(f[j]);
    ((u16x8*)y)[i] = o;
  }
}

__global__ void cvt_w_kernel(const int* __restrict__ t, const float* __restrict__ s,
                             unsigned short* __restrict__ w, int n8) {
  int stride = gridDim.x * blockDim.x;
  for (int i = blockIdx.x * blockDim.x + threadIdx.x; i < n8; i += stride) {
    i32x4 a = ((const i32x4*)t)[2 * i + 0];
    i32x4 b = ((const i32x4*)t)[2 * i + 1];
    float sc = s[i >> 4];
    u16x8 o;
    o[0] = f2bf((float)a[0] * sc); o[1] = f2bf((float)a[1] * sc);
    o[2] = f2bf((float)a[2] * sc); o[3] = f2bf((float)a[3] * sc);
    o[4] = f2bf((float)b[0] * sc); o[5] = f2bf((float)b[1] * sc);
    o[6] = f2bf((float)b[2] * sc); o[7] = f2bf((float)b[3] * sc);
    ((u16x8*)w)[i] = o;
  }
}

// ---------------------------------------------------------------------------
// 256x256x64 8-wave 8-phase GEMM. A [M][K] bf16, B [N][K] bf16, C [M][N] f32.
// LDS (dynamic, 128 KiB): buf c at c*65536: A tile [256][64] (32KB), then B.
// T2 swizzle: element (row,col) lives at byte row*128 + ((col*2) ^ ((row&7)<<4)).
// Staged via linear global_load_lds dest + inverse-swizzled global source.
// ---------------------------------------------------------------------------
__global__ __launch_bounds__(THREADS, 2)
void gemm256_kernel(const unsigned short* __restrict__ A,
                    const unsigned short* __restrict__ B,
                    float* __restrict__ C) {
  extern __shared__ char smem[];

  const int tid  = threadIdx.x;
  const int lane = tid & 63;
  const int wave = tid >> 6;     // 0..7
  const int wm   = wave >> 2;    // 0..1  (M half)
  const int wn   = wave & 3;     // 0..3  (N quarter)

  // T1: XCD-bijective swizzle; grid = 512, 512 % 8 == 0.
  const int blk = blockIdx.x;
  const int wg  = (blk & 7) * (512 / 8) + (blk >> 3);
  const int bm  = wg >> 4;       // 32 M-blocks
  const int bn  = wg & 15;       // 16 N-blocks

  // Staging source (per-thread, inverse-swizzled): thread covers LDS bytes
  // [j*8192 + wave*1024 + lane*16) -> row = j*64 + tid/8, colbyte = (tid&7)*16.
  const int srow = tid >> 3;                         // 0..63
  const int scol = 8 * ((tid & 7) ^ (srow & 7));     // swizzled col (elements)
  const unsigned short* Ap = A + (size_t)(bm * BM + srow) * K_DIM + scol;
  const unsigned short* Bp = B + (size_t)(bn * BN + srow) * K_DIM + scol;
  const int ldsWave = wave * 1024;

  // ab: 0 = A tile, 1 = B tile. j in 0..3 covers rows [64j, 64j+64).
  auto STAGE = [&](int c, int ab, int T, int j) {
    const unsigned short* src =
        (ab == 0 ? Ap : Bp) + (size_t)j * 64 * K_DIM + (size_t)T * BK;
    char* dst = smem + c * 65536 + ab * 32768 + j * 8192 + ldsWave;
    __builtin_amdgcn_global_load_lds(
        (const __attribute__((address_space(1))) void*)src,
        (__attribute__((address_space(3))) void*)dst, 16, 0, 0);
  };

  // Fragment reads (swizzled): row&7 == lane&7 for all frags (16-row aligned).
  const int r   = lane & 15;
  const int kq  = lane >> 4;
  const int swz = (lane & 7) << 3;   // element-space XOR
  auto RD_A = [&](int c, int mf, int ks) -> bf16x8 {
    const int row = wm * 128 + mf * 16 + r;
    const int col = (ks * 32 + kq * 8) ^ swz;
    return *(const bf16x8*)(smem + c * 65536 + (row * 64 + col) * 2);
  };
  auto RD_B = [&](int c, int nf, int ks) -> bf16x8 {
    const int row = wn * 64 + nf * 16 + r;
    const int col = (ks * 32 + kq * 8) ^ swz;
    return *(const bf16x8*)(smem + c * 65536 + 32768 + (row * 64 + col) * 2);
  };

  const f32x4 fzero = {0.f, 0.f, 0.f, 0.f};
  f32x4 acc[8][4];
#pragma unroll
  for (int mf = 0; mf < 8; ++mf)
#pragma unroll
    for (int nf = 0; nf < 4; ++nf) acc[mf][nf] = fzero;

  // ---- prologue: tile0 (A+B) -> buf0; tile1 B -> buf1 ----
#pragma unroll
  for (int j = 0; j < 4; ++j) STAGE(0, 0, 0, j);
#pragma unroll
  for (int j = 0; j < 4; ++j) STAGE(0, 1, 0, j);
#pragma unroll
  for (int j = 0; j < 4; ++j) STAGE(1, 1, 1, j);
  asm volatile("s_waitcnt vmcnt(4)" ::: "memory");  // tile0 fully landed
  __builtin_amdgcn_s_barrier();

  for (int t = 0; t < NT; ++t) {
    const int cur = t & 1;
    const int nxt = cur ^ 1;
    bf16x8 aLo[4][2], aHi[4][2], bF[4][2];

    // ===== P1: quadrant (m0-3 x n0-1). reads: A-lo (8) + B-lo (4) =====
#pragma unroll
    for (int mf = 0; mf < 4; ++mf)
#pragma unroll
      for (int ks = 0; ks < 2; ++ks) aLo[mf][ks] = RD_A(cur, mf, ks);
#pragma unroll
    for (int nf = 0; nf < 2; ++nf)
#pragma unroll
      for (int ks = 0; ks < 2; ++ks) bF[nf][ks] = RD_B(cur, nf, ks);
    if (t + 1 < NT) { STAGE(nxt, 0, t + 1, 0); STAGE(nxt, 0, t + 1, 1); }
    __builtin_amdgcn_s_barrier();
    asm volatile("s_waitcnt lgkmcnt(0)" ::: "memory");
    __builtin_amdgcn_sched_barrier(0);
    __builtin_amdgcn_s_setprio(1);
#pragma unroll
    for (int mf = 0; mf < 4; ++mf)
#pragma unroll
      for (int nf = 0; nf < 2; ++nf)
#pragma unroll
        for (int ks = 0; ks < 2; ++ks)
          acc[mf][nf] = __builtin_amdgcn_mfma_f32_16x16x32_bf16(
              aLo[mf][ks], bF[nf][ks], acc[mf][nf], 0, 0, 0);
    __builtin_amdgcn_s_setprio(0);
    __builtin_amdgcn_s_barrier();

    // ===== P2: quadrant (m0-3 x n2-3). reads: B-hi (4) =====
#pragma unroll
    for (int nf = 2; nf < 4; ++nf)
#pragma unroll
      for (int ks = 0; ks < 2; ++ks) bF[nf][ks] = RD_B(cur, nf, ks);
    if (t + 1 < NT) { STAGE(nxt, 0, t + 1, 2); STAGE(nxt, 0, t + 1, 3); }
    __builtin_amdgcn_s_barrier();
    asm volatile("s_waitcnt lgkmcnt(0)" ::: "memory");
    __builtin_amdgcn_sched_barrier(0);
    __builtin_amdgcn_s_setprio(1);
#pragma unroll
    for (int mf = 0; mf < 4; ++mf)
#pragma unroll
      for (int nf = 2; nf < 4; ++nf)
#pragma unroll
        for (int ks = 0; ks < 2; ++ks)
          acc[mf][nf] = __builtin_amdgcn_mfma_f32_16x16x32_bf16(
              aLo[mf][ks], bF[nf][ks], acc[mf][nf], 0, 0, 0);
    __builtin_amdgcn_s_setprio(0);
    __builtin_amdgcn_s_barrier();

    // ===== P3: quadrant (m4-7 x n0-1). reads: A-hi (8) =====
    // B region of buf[cur] fully read (P2-end barrier) -> stage t+2 B there.
#pragma unroll
    for (int mf = 0; mf < 4; ++mf)
#pragma unroll
      for (int ks = 0; ks < 2; ++ks) aHi[mf][ks] = RD_A(cur, mf + 4, ks);
    if (t + 2 < NT) { STAGE(cur, 1, t + 2, 0); STAGE(cur, 1, t + 2, 1); }
    __builtin_amdgcn_s_barrier();
    asm volatile("s_waitcnt lgkmcnt(0)" ::: "memory");
    __builtin_amdgcn_sched_barrier(0);
    __builtin_amdgcn_s_setprio(1);
#pragma unroll
    for (int mf = 0; mf < 4; ++mf)
#pragma unroll
      for (int nf = 0; nf < 2; ++nf)
#pragma unroll
        for (int ks = 0; ks < 2; ++ks)
          acc[mf + 4][nf] = __builtin_amdgcn_mfma_f32_16x16x32_bf16(
              aHi[mf][ks], bF[nf][ks], acc[mf + 4][nf], 0, 0, 0);
    __builtin_amdgcn_s_setprio(0);
    __builtin_amdgcn_s_barrier();

    // ===== P4: quadrant (m4-7 x n2-3). no reads =====
    if (t + 2 < NT) { STAGE(cur, 1, t + 2, 2); STAGE(cur, 1, t + 2, 3); }
    __builtin_amdgcn_s_barrier();
    __builtin_amdgcn_s_setprio(1);
#pragma unroll
    for (int mf = 0; mf < 4; ++mf)
#pragma unroll
      for (int nf = 2; nf < 4; ++nf)
#pragma unroll
        for (int ks = 0; ks < 2; ++ks)
          acc[mf + 4][nf] = __builtin_amdgcn_mfma_f32_16x16x32_bf16(
              aHi[mf][ks], bF[nf][ks], acc[mf + 4][nf], 0, 0, 0);
    __builtin_amdgcn_s_setprio(0);
    // iteration end: tile t+1 must be fully landed before next P1 reads it.
    if (t + 2 < NT) {
      asm volatile("s_waitcnt vmcnt(4)" ::: "memory");  // leave t+2's 4 B-loads
    } else if (t + 1 < NT) {
      asm volatile("s_waitcnt vmcnt(0)" ::: "memory");
    }
    __builtin_amdgcn_s_barrier();
  }

  // ---- epilogue: C/D map col = lane&15, row = (lane>>4)*4 + j ----
  const int r4 = (lane >> 4) * 4;
  const int cc = lane & 15;
  const size_t row0 = (size_t)bm * BM + wm * 128;
  const size_t col0 = (size_t)bn * BN + wn * 64;
#pragma unroll
  for (int mf = 0; mf < 8; ++mf)
#pragma unroll
    for (int nf = 0; nf < 4; ++nf)
#pragma unroll
      for (int j = 0; j < 4; ++j)
        C[(row0 + mf * 16 + r4 + j) * N_DIM + col0 + nf * 16 + cc] =
            acc[mf][nf][j];
}

extern "C" void kernel_launch(void* const* d_in, const int* in_sizes, int n_in,
                              void* d_out, int out_size, void* d_ws, size_t ws_size,
                              hipStream_t stream) {
  const float* x      = (const float*)d_in[0];
  const int*   tern   = (const int*)d_in[1];
  const float* scales = (const float*)d_in[2];
  float* out = (float*)d_out;

  unsigned short* xb = (unsigned short*)d_ws;
  unsigned short* wb = (unsigned short*)d_ws + (size_t)M_DIM * K_DIM;

  cvt_x_kernel<<<2048, 256, 0, stream>>>(x, xb, M_DIM * K_DIM / 8);
  cvt_w_kernel<<<2048, 256, 0, stream>>>(tern, scales, wb, N_DIM * K_DIM / 8);

  // 128 KiB dynamic LDS needs the opt-in attribute (host-side, capture-safe).
  hipFuncSetAttribute((const void*)gemm256_kernel,
                      hipFuncAttributeMaxDynamicSharedMemorySize, 131072);
  const int grid = (M_DIM / BM) * (N_DIM / BN);  // 32 * 16 = 512
  gemm256_kernel<<<grid, THREADS, 131072, stream>>>(xb, wb, out);
}